// Round 13
// baseline (72.858 us; speedup 1.0000x reference)
//
#include <hip/hip_runtime.h>
#include <hip/hip_bf16.h>

#define T_LEN   2000
#define NKER    256
#define LPAD    128          // padded l-dim (Lmax <= 127)
#define NE      2128         // shifted entries staged (>= T_LEN + Lmax - 1)
#define THREADS 512

typedef int   v4i __attribute__((ext_vector_type(4)));
typedef float v4f __attribute__((ext_vector_type(4)));

// raw-asm MFMA. "=&v" early-clobber: D must not alias A/B (multi-pass XDL).
__device__ inline v4f mfma_z(v4i a, v4i b, v4f c) {
    v4f d;
    asm volatile("v_mfma_f32_16x16x32_bf16 %0, %1, %2, %3"
                 : "=&v"(d) : "v"(a), "v"(b), "v"(c));
    return d;
}
__device__ inline v4f mfma_z_last(v4i a, v4i b, v4f c) {
    v4f d;
    asm volatile("v_mfma_f32_16x16x32_bf16 %0, %1, %2, %3\n\ts_nop 7"
                 : "=&v"(d) : "v"(a), "v"(b), "v"(c));
    return d;
}
__device__ inline void mfma_acc(v4f& acc, v4i a, v4i b) {
    asm volatile("v_mfma_f32_16x16x32_bf16 %0, %1, %2, %0"
                 : "+v"(acc) : "v"(a), "v"(b));
}
__device__ inline void mfma_acc_last(v4f& acc, v4i a, v4i b) {
    asm volatile("v_mfma_f32_16x16x32_bf16 %0, %1, %2, %0\n\ts_nop 7"
                 : "+v"(acc) : "v"(a), "v"(b));
}

__device__ inline unsigned f2bf(float f) {
    return (unsigned)__builtin_bit_cast(unsigned short, __float2bfloat16(f));
}

// ---------------------------------------------------------------------------
// Sort (bulletproof-by-construction): per-kernel ns from nonzero span, then
// O(N^2) comparator rank (stable ascending) -> pos is ALWAYS a permutation;
// tile_ns via atomicMax over the tile's actual members -> tile_ns >= each
// member's ns holds regardless of ordering.
// ---------------------------------------------------------------------------
__global__ void rocket_sort(const float* __restrict__ W,
                            const float* __restrict__ bias, int Lmax,
                            int* __restrict__ perm, int* __restrict__ tile_ns,
                            float* __restrict__ bias_s) {
    __shared__ int ns_sh[NKER];
    __shared__ int tmax[16];
    const int k = threadIdx.x;
    int lf = 1 << 20, ll = -1;
    for (int l = 0; l < Lmax; ++l) {
        float v = W[k * Lmax + l];
        if (v != 0.0f) { if (l < lf) lf = l; ll = l; }
    }
    int a = 64 - lf, b = ll - 63;
    int m = a > b ? a : b;
    if (m < 1) m = 1;
    if (m > 64) m = 64;
    const int ns = (m + 15) >> 4;        // 1..4; window [64-16ns, 64+16ns)
    ns_sh[k] = ns;
    if (k < 16) tmax[k] = 1;
    __syncthreads();
    int pos = 0;
    for (int j = 0; j < NKER; ++j) {
        int nj = ns_sh[j];
        pos += (nj < ns || (nj == ns && j < k)) ? 1 : 0;
    }
    perm[pos]   = k;
    bias_s[pos] = bias[k];
    atomicMax(&tmax[pos >> 4], ns);
    __syncthreads();
    if (k < 16) tile_ns[k] = tmax[k];
}

// ---------------------------------------------------------------------------
// Prep: bf16 weight bank in SORTED order: Wbf[pos][l] = W[perm[pos]][l].
// ---------------------------------------------------------------------------
__global__ void rocket_prep(const float* __restrict__ W, int Lmax,
                            const int* __restrict__ perm,
                            unsigned* __restrict__ Wbf32) {
    const int pos = blockIdx.x;
    const int k   = perm[pos];
    const int t   = threadIdx.x;         // 0..63
    const int l0 = 2 * t, l1 = 2 * t + 1;
    float v0 = (l0 < Lmax) ? W[k * Lmax + l0] : 0.0f;
    float v1 = (l1 < Lmax) ? W[k * Lmax + l1] : 0.0f;
    Wbf32[pos * (LPAD / 2) + t] = f2bf(v0) | (f2bf(v1) << 16);
}

// chain for one ktile with wave-uniform NS; B operands are the named per-tile
// entries q_o (o = (4-NS) + 2s), all static names -> registers.
#define CHAIN(kt, NS)                                                        \
    {                                                                        \
        v4f acc;                                                             \
        switch (NS) {                                                        \
        case 1:                                                              \
            acc = mfma_z_last(afrag[kt][0], q3, zero4);                      \
            break;                                                           \
        case 2:                                                              \
            acc = mfma_z(afrag[kt][0], q2, zero4);                           \
            mfma_acc_last(acc, afrag[kt][1], q4);                            \
            break;                                                           \
        case 3:                                                              \
            acc = mfma_z(afrag[kt][0], q1, zero4);                           \
            mfma_acc(acc, afrag[kt][1], q3);                                 \
            mfma_acc_last(acc, afrag[kt][2], q5);                            \
            break;                                                           \
        default:                                                             \
            acc = mfma_z(afrag[kt][0], q0, zero4);                           \
            mfma_acc(acc, afrag[kt][1], q2);                                 \
            mfma_acc(acc, afrag[kt][2], q4);                                 \
            mfma_acc_last(acc, afrag[kt][3], q6);                            \
            break;                                                           \
        }                                                                    \
        _Pragma("unroll")                                                    \
        for (int r = 0; r < 4; ++r) {                                        \
            cnt[kt][r] += (acc[r] > nb[kt][r]) ? 1u : 0u;                    \
            mx[kt][r]  = fmaxf(mx[kt][r], acc[r]);                           \
        }                                                                    \
    }

// ---------------------------------------------------------------------------
// Main: grid (256 bc, 4 sub) x 512 threads (8 waves = 2 kp x 4 tq).
// Block owns SORTED ktiles {sub, sub+4, sub+8, sub+12}; wave kp handles tiles
// sub+4*(2kp), sub+4*(2kp+1) over 32/29 t-tiles. Per tile: load the UNION of
// B entries the two ns-chains need (q0..q6, wave-uniform flags), then 2
// switch-chains (ns MFMAs each). No sliding window. Output scatter via perm.
// ---------------------------------------------------------------------------
__global__ __launch_bounds__(THREADS, 4) void rocket_main(
    const float* __restrict__ x, const float* __restrict__ bias_s,
    const unsigned short* __restrict__ Wbf, const int* __restrict__ perm,
    const int* __restrict__ tile_ns, float* __restrict__ out, int Lmax) {

    __shared__ __align__(16) uint4 sx8[2400];     // idx max 2392
    __shared__ unsigned pc[64][4];
    __shared__ float    pm[64][4];

    const int bc  = blockIdx.x;
    const int sub = blockIdx.y;
    const int tid = threadIdx.x;
    const int c0  = (Lmax - 1) >> 1;

    // ---- stage shifted entries: 5 consecutive entries per thread ----
    {
        const int base = tid * 5;
        if (base < NE) {
            float xv[12];
            #pragma unroll
            for (int i = 0; i < 12; ++i) {
                int s = base + i - c0;
                xv[i] = (s >= 0 && s < T_LEN) ? x[bc * T_LEN + s] : 0.0f;
            }
            unsigned hb[12];
            #pragma unroll
            for (int i = 0; i < 12; ++i) hb[i] = f2bf(xv[i]);
            #pragma unroll
            for (int i = 0; i < 5; ++i) {
                int p = base + i;
                if (p < NE) {
                    uint4 v;
                    v.x = hb[i]     | (hb[i + 1] << 16);
                    v.y = hb[i + 2] | (hb[i + 3] << 16);
                    v.z = hb[i + 4] | (hb[i + 5] << 16);
                    v.w = hb[i + 6] | (hb[i + 7] << 16);
                    sx8[p + (p >> 3)] = v;
                }
            }
        }
    }

    const int lane = tid & 63;
    const int wid  = tid >> 6;
    const int kp   = wid >> 2;
    const int tq   = wid & 3;
    const int g    = lane >> 4;
    const int c    = lane & 15;

    const int tile0 = sub + 4 * (kp * 2 + 0);
    const int tile1 = sub + 4 * (kp * 2 + 1);
    int ns0 = __builtin_amdgcn_readfirstlane(tile_ns[tile0]);
    int ns1 = __builtin_amdgcn_readfirstlane(tile_ns[tile1]);
    ns0 = ns0 < 1 ? 1 : (ns0 > 4 ? 4 : ns0);     // defensive clamp
    ns1 = ns1 < 1 ? 1 : (ns1 > 4 ? 4 : ns1);

    // ---- A fragments: k-window only (s < ns), l0 = 16*(4-ns) ----
    v4i afrag[2][4];
    #pragma unroll
    for (int kt = 0; kt < 2; ++kt) {
        const int tld = (kt == 0) ? tile0 : tile1;
        const int nsk = (kt == 0) ? ns0 : ns1;
        const int l0  = 16 * (4 - nsk);
        #pragma unroll
        for (int s = 0; s < 4; ++s) {
            if (s < nsk) {
                const unsigned short* src =
                    Wbf + (tld * 16 + c) * LPAD + l0 + s * 32 + g * 8;
                afrag[kt][s] = *reinterpret_cast<const v4i*>(src);
            }
        }
    }

    // ---- negated sorted bias per owned row ----
    float nb[2][4];
    #pragma unroll
    for (int kt = 0; kt < 2; ++kt) {
        const int tld = (kt == 0) ? tile0 : tile1;
        float4 bv = *reinterpret_cast<const float4*>(bias_s + tld * 16 + g * 4);
        nb[kt][0] = -bv.x; nb[kt][1] = -bv.y;
        nb[kt][2] = -bv.z; nb[kt][3] = -bv.w;
    }

    __syncthreads();

    unsigned cnt[2][4] = {};
    float    mx[2][4];
    #pragma unroll
    for (int kt = 0; kt < 2; ++kt)
        #pragma unroll
        for (int r = 0; r < 4; ++r) mx[kt][r] = -__builtin_inff();

    v4f zero4 = {0.f, 0.f, 0.f, 0.f};
    asm("" : "+v"(zero4));   // pin: persistent zero C-quad

    const int pb = g * 8 + c;                        // 0..39
    const unsigned voff = (unsigned)(pb + (pb >> 3)) << 4;

    // entry-union need flags: chain ns uses offsets o = (4-ns)+2s, s<ns,
    // i.e. same parity as ns, 4-ns <= o <= ns+2. Wave-uniform.
    #define NEEDO(o) ((((o) ^ ns0) & 1) == 0 && (o) >= 4 - ns0 && (o) <= ns0 + 2) || \
                     ((((o) ^ ns1) & 1) == 0 && (o) >= 4 - ns1 && (o) <= ns1 + 2)
    const bool nd0 = NEEDO(0), nd1 = NEEDO(1), nd2 = NEEDO(2), nd3 = NEEDO(3),
               nd4 = NEEDO(4), nd5 = NEEDO(5), nd6 = NEEDO(6);
    #undef NEEDO

    const int tstart = tq * 32;                      // 32/32/32/29 split
    const int nt     = (tq == 3) ? 29 : 32;

    // entry J at byte 288*J + voff
    const char* p = (const char*)sx8 + voff + 288u * (unsigned)tstart;

    #pragma unroll 1
    for (int tt = 0; tt < nt; ++tt) {
        const char* q = p + 288 * tt;
        v4i q0, q1, q2, q3, q4, q5, q6;
        if (nd0) q0 = *reinterpret_cast<const v4i*>(q);
        if (nd1) q1 = *reinterpret_cast<const v4i*>(q + 288);
        if (nd2) q2 = *reinterpret_cast<const v4i*>(q + 576);
        if (nd3) q3 = *reinterpret_cast<const v4i*>(q + 864);
        if (nd4) q4 = *reinterpret_cast<const v4i*>(q + 1152);
        if (nd5) q5 = *reinterpret_cast<const v4i*>(q + 1440);
        if (nd6) q6 = *reinterpret_cast<const v4i*>(q + 1728);
        CHAIN(0, ns0)
        CHAIN(1, ns1)
    }

    // ---- col reduce over 16 lanes via DPP row_ror (no LDS pipe) ----
    #pragma unroll
    for (int kt = 0; kt < 2; ++kt) {
        #pragma unroll
        for (int r = 0; r < 4; ++r) {
            unsigned cv = cnt[kt][r];
            cv += (unsigned)__builtin_amdgcn_update_dpp(0, (int)cv, 0x128, 0xF, 0xF, true);
            cv += (unsigned)__builtin_amdgcn_update_dpp(0, (int)cv, 0x124, 0xF, 0xF, true);
            cv += (unsigned)__builtin_amdgcn_update_dpp(0, (int)cv, 0x122, 0xF, 0xF, true);
            cv += (unsigned)__builtin_amdgcn_update_dpp(0, (int)cv, 0x121, 0xF, 0xF, true);
            float mv = mx[kt][r];
            mv = fmaxf(mv, __builtin_bit_cast(float,
                 __builtin_amdgcn_update_dpp(0, __builtin_bit_cast(int, mv), 0x128, 0xF, 0xF, true)));
            mv = fmaxf(mv, __builtin_bit_cast(float,
                 __builtin_amdgcn_update_dpp(0, __builtin_bit_cast(int, mv), 0x124, 0xF, 0xF, true)));
            mv = fmaxf(mv, __builtin_bit_cast(float,
                 __builtin_amdgcn_update_dpp(0, __builtin_bit_cast(int, mv), 0x122, 0xF, 0xF, true)));
            mv = fmaxf(mv, __builtin_bit_cast(float,
                 __builtin_amdgcn_update_dpp(0, __builtin_bit_cast(int, mv), 0x121, 0xF, 0xF, true)));
            if (c == 0) {
                const int klo = (kp * 2 + kt) * 16 + g * 4 + r;   // 0..63
                pc[klo][tq] = cv;
                pm[klo][tq] = mv;
            }
        }
    }
    __syncthreads();

    if (tid < 64) {
        unsigned ct = pc[tid][0] + pc[tid][1] + pc[tid][2] + pc[tid][3];
        float mv = fmaxf(fmaxf(pm[tid][0], pm[tid][1]),
                         fmaxf(pm[tid][2], pm[tid][3]));
        const int tpos = tid >> 4, row = tid & 15;
        const int pos  = (sub + 4 * tpos) * 16 + row;   // sorted position
        const int kk   = perm[pos];                     // original kernel id
        out[bc * (2 * NKER) + 2 * kk]     = (float)ct * (1.0f / T_LEN);
        out[bc * (2 * NKER) + 2 * kk + 1] = mv + bias_s[pos];
    }
}

extern "C" void kernel_launch(void* const* d_in, const int* in_sizes, int n_in,
                              void* d_out, int out_size, void* d_ws, size_t ws_size,
                              hipStream_t stream) {
    const float* x    = (const float*)d_in[0];
    const float* W    = (const float*)d_in[1];
    const float* bias = (const float*)d_in[2];
    float*       out  = (float*)d_out;

    const int Lmax = in_sizes[1] / NKER;

    unsigned* Wbf32   = (unsigned*)d_ws;                       // 64 KB
    int*      perm    = (int*)((char*)d_ws + 65536);           // 1 KB
    float*    bias_s  = (float*)((char*)d_ws + 66560);         // 1 KB
    int*      tile_ns = (int*)((char*)d_ws + 67584);           // 64 B

    rocket_sort<<<dim3(1), dim3(NKER), 0, stream>>>(W, bias, Lmax,
                                                    perm, tile_ns, bias_s);
    rocket_prep<<<dim3(NKER), dim3(64), 0, stream>>>(W, Lmax, perm, Wbf32);
    rocket_main<<<dim3(256, 4), dim3(THREADS), 0, stream>>>(
        x, bias_s, (const unsigned short*)Wbf32, perm, tile_ns, out, Lmax);
}

// Round 15
// 53.695 us; speedup vs baseline: 1.3569x; 1.3569x over previous
//
#include <hip/hip_runtime.h>
#include <hip/hip_bf16.h>

#define T_LEN   2000
#define NKER    256
#define LPAD    128          // padded l-dim (Lmax <= 127)
#define NE      2128         // shifted entries staged (>= T_LEN + Lmax - 1)
#define THREADS 512

typedef int   v4i __attribute__((ext_vector_type(4)));
typedef float v4f __attribute__((ext_vector_type(4)));

// raw-asm MFMA. "=&v" early-clobber: D must not alias A/B (multi-pass XDL).
__device__ inline v4f mfma_z(v4i a, v4i b, v4f c) {
    v4f d;
    asm volatile("v_mfma_f32_16x16x32_bf16 %0, %1, %2, %3"
                 : "=&v"(d) : "v"(a), "v"(b), "v"(c));
    return d;
}
__device__ inline v4f mfma_z_last(v4i a, v4i b, v4f c) {
    v4f d;
    asm volatile("v_mfma_f32_16x16x32_bf16 %0, %1, %2, %3\n\ts_nop 7"
                 : "=&v"(d) : "v"(a), "v"(b), "v"(c));
    return d;
}
__device__ inline void mfma_acc(v4f& acc, v4i a, v4i b) {
    asm volatile("v_mfma_f32_16x16x32_bf16 %0, %1, %2, %0"
                 : "+v"(acc) : "v"(a), "v"(b));
}
__device__ inline void mfma_acc_last(v4f& acc, v4i a, v4i b) {
    asm volatile("v_mfma_f32_16x16x32_bf16 %0, %1, %2, %0\n\ts_nop 7"
                 : "+v"(acc) : "v"(a), "v"(b));
}

__device__ inline unsigned f2bf(float f) {
    return (unsigned)__builtin_bit_cast(unsigned short, __float2bfloat16(f));
}

// ---------------------------------------------------------------------------
// Scan: per-kernel ns (256 blocks x 64 thr, wave-reduce span min/max).
// ns = ceil(max(64-lf, ll-63)/16) in 1..4; k-window [64-16ns, 64+16ns).
// ---------------------------------------------------------------------------
__global__ void rocket_scan(const float* __restrict__ W, int Lmax,
                            int* __restrict__ ns_arr) {
    const int k = blockIdx.x;
    const int t = threadIdx.x;           // 0..63
    const int l0 = 2 * t, l1 = 2 * t + 1;
    float v0 = (l0 < Lmax) ? W[k * Lmax + l0] : 0.0f;
    float v1 = (l1 < Lmax) ? W[k * Lmax + l1] : 0.0f;
    int lo = 1 << 20, hi = -1;
    if (v0 != 0.0f) { lo = l0; hi = l0; }
    if (v1 != 0.0f) { if (l1 < lo) lo = l1; hi = l1; }
    #pragma unroll
    for (int m = 32; m >= 1; m >>= 1) {
        int ol = __shfl_xor(lo, m, 64);
        int oh = __shfl_xor(hi, m, 64);
        lo = ol < lo ? ol : lo;
        hi = oh > hi ? oh : hi;
    }
    if (t == 0) {
        int a = 64 - lo, b = hi - 63;
        int m = a > b ? a : b;
        if (m < 1) m = 1;
        if (m > 64) m = 64;
        ns_arr[k] = (m + 15) >> 4;       // 1..4
    }
}

// ---------------------------------------------------------------------------
// Rank: stable ascending-ns comparator rank (always a permutation).
// ---------------------------------------------------------------------------
__global__ void rocket_rank(const int* __restrict__ ns_arr,
                            const float* __restrict__ bias,
                            int* __restrict__ perm, int* __restrict__ ns_s,
                            float* __restrict__ bias_s) {
    __shared__ int ns_sh[NKER];
    const int k = threadIdx.x;
    ns_sh[k] = ns_arr[k];
    __syncthreads();
    const int ns = ns_sh[k];
    int pos = 0;
    for (int j = 0; j < NKER; ++j) {
        int nj = ns_sh[j];
        pos += (nj < ns || (nj == ns && j < k)) ? 1 : 0;
    }
    perm[pos]   = k;
    bias_s[pos] = bias[k];
    ns_s[pos]   = ns;
}

// ---------------------------------------------------------------------------
// Prep: bf16 weight bank in SORTED order: Wbf[pos][l] = W[perm[pos]][l].
// ---------------------------------------------------------------------------
__global__ void rocket_prep(const float* __restrict__ W, int Lmax,
                            const int* __restrict__ perm,
                            unsigned* __restrict__ Wbf32) {
    const int pos = blockIdx.x;
    const int k   = perm[pos];
    const int t   = threadIdx.x;         // 0..63
    const int l0 = 2 * t, l1 = 2 * t + 1;
    float v0 = (l0 < Lmax) ? W[k * Lmax + l0] : 0.0f;
    float v1 = (l1 < Lmax) ? W[k * Lmax + l1] : 0.0f;
    Wbf32[pos * (LPAD / 2) + t] = f2bf(v0) | (f2bf(v1) << 16);
}

// ---------------------------------------------------------------------------
// Stride-2-tile sweep, NS compile-time. Tile T needs entry groups
// T + (4-NS) + 2s (s<NS); tile T+2 needs them shifted by one slot.
// State e[NS] (<=4 v4i), shift-by-one + 1 ds_read per tile. All register
// indices compile-time; no switch in loop; no modular renaming.
// ---------------------------------------------------------------------------
template<int NS>
__device__ __attribute__((always_inline)) void sweep(
    const char* pb, int t0, int nt,
    const v4i (&af)[2][4], const float (&nb)[2][4],
    unsigned (&cnt)[2][4], float (&mx)[2][4], v4f zero4)
{
    const char* q = pb + 288u * (unsigned)(t0 + (4 - NS));  // group of e[0], tile t0
    v4i e[NS];
    #pragma unroll
    for (int i = 0; i < NS; ++i)
        e[i] = *reinterpret_cast<const v4i*>(q + 288 * (2 * i));

    #pragma unroll 1
    for (int it = 0; it < nt; ++it) {
        #pragma unroll
        for (int kt = 0; kt < 2; ++kt) {
            v4f acc;
            if (NS == 1) {
                acc = mfma_z_last(af[kt][0], e[0], zero4);
            } else {
                acc = mfma_z(af[kt][0], e[0], zero4);
                #pragma unroll
                for (int s = 1; s < NS - 1; ++s)
                    mfma_acc(acc, af[kt][s], e[s]);
                mfma_acc_last(acc, af[kt][NS - 1], e[NS - 1]);
            }
            #pragma unroll
            for (int r = 0; r < 4; ++r) {
                cnt[kt][r] += (acc[r] > nb[kt][r]) ? 1u : 0u;
                mx[kt][r]  = fmaxf(mx[kt][r], acc[r]);
            }
        }
        if (it + 1 < nt) {
            #pragma unroll
            for (int i = 0; i + 1 < NS; ++i) e[i] = e[i + 1];
            // new top for tile t0+2(it+1): group (t0+J0) + 2NS + 2it
            e[NS - 1] = *reinterpret_cast<const v4i*>(q + 288 * (2 * NS + 2 * it));
        }
    }
}

// ---------------------------------------------------------------------------
// Main: grid (256 bc, 4 sub) x 512 threads (8 waves = 2 kp x 4 tq).
// Wave owns ADJACENT sorted ktiles sub*4+2kp, sub*4+2kp+1 (equal-ns pairs);
// pair ns = ns_s[last row of pair] (ascending sort => range max). A-window
// l0 = 16*(4-ns) for both (zero-padded => exact). t-quarter split 32/32/32/29,
// each done as even-tiles sweep + odd-tiles sweep (stride 2, 1 read/tile).
// ---------------------------------------------------------------------------
__global__ __launch_bounds__(THREADS, 4) void rocket_main(
    const float* __restrict__ x, const float* __restrict__ bias_s,
    const unsigned short* __restrict__ Wbf, const int* __restrict__ perm,
    const int* __restrict__ ns_s, float* __restrict__ out, int Lmax) {

    __shared__ __align__(16) uint4 sx8[2400];     // idx max 2392
    __shared__ unsigned pc[64][4];
    __shared__ float    pm[64][4];

    const int bc  = blockIdx.x;
    const int sub = blockIdx.y;
    const int tid = threadIdx.x;
    const int c0  = (Lmax - 1) >> 1;

    // ---- stage shifted entries: 5 consecutive entries per thread ----
    {
        const int base = tid * 5;
        if (base < NE) {
            float xv[12];
            #pragma unroll
            for (int i = 0; i < 12; ++i) {
                int s = base + i - c0;
                xv[i] = (s >= 0 && s < T_LEN) ? x[bc * T_LEN + s] : 0.0f;
            }
            unsigned hb[12];
            #pragma unroll
            for (int i = 0; i < 12; ++i) hb[i] = f2bf(xv[i]);
            #pragma unroll
            for (int i = 0; i < 5; ++i) {
                int p = base + i;
                if (p < NE) {
                    uint4 v;
                    v.x = hb[i]     | (hb[i + 1] << 16);
                    v.y = hb[i + 2] | (hb[i + 3] << 16);
                    v.z = hb[i + 4] | (hb[i + 5] << 16);
                    v.w = hb[i + 6] | (hb[i + 7] << 16);
                    sx8[p + (p >> 3)] = v;
                }
            }
        }
    }

    const int lane = tid & 63;
    const int wid  = tid >> 6;
    const int kp   = wid >> 2;
    const int tq   = wid & 3;
    const int g    = lane >> 4;
    const int c    = lane & 15;

    const int tile0 = sub * 4 + kp * 2;          // adjacent sorted pair
    const int tile1 = tile0 + 1;
    int ns = __builtin_amdgcn_readfirstlane(ns_s[tile1 * 16 + 15]);
    ns = ns < 1 ? 1 : (ns > 4 ? 4 : ns);         // defensive clamp

    // ---- A fragments: shared pair window l0 = 16*(4-ns), s < ns ----
    v4i afrag[2][4];
    const int l0 = 16 * (4 - ns);
    #pragma unroll
    for (int kt = 0; kt < 2; ++kt) {
        const int tld = (kt == 0) ? tile0 : tile1;
        #pragma unroll
        for (int s = 0; s < 4; ++s) {
            if (s < ns) {
                const unsigned short* src =
                    Wbf + (tld * 16 + c) * LPAD + l0 + s * 32 + g * 8;
                afrag[kt][s] = *reinterpret_cast<const v4i*>(src);
            }
        }
    }

    // ---- negated sorted bias per owned row ----
    float nb[2][4];
    #pragma unroll
    for (int kt = 0; kt < 2; ++kt) {
        const int tld = (kt == 0) ? tile0 : tile1;
        float4 bv = *reinterpret_cast<const float4*>(bias_s + tld * 16 + g * 4);
        nb[kt][0] = -bv.x; nb[kt][1] = -bv.y;
        nb[kt][2] = -bv.z; nb[kt][3] = -bv.w;
    }

    __syncthreads();

    unsigned cnt[2][4] = {};
    float    mx[2][4];
    #pragma unroll
    for (int kt = 0; kt < 2; ++kt)
        #pragma unroll
        for (int r = 0; r < 4; ++r) mx[kt][r] = -__builtin_inff();

    v4f zero4 = {0.f, 0.f, 0.f, 0.f};
    asm("" : "+v"(zero4));   // pin: persistent zero C-quad

    const int pb = g * 8 + c;                        // 0..39
    const unsigned voff = (unsigned)(pb + (pb >> 3)) << 4;
    const char* sxb = (const char*)sx8 + voff;

    const int tstart = tq * 32;                      // 32/32/32/29 split
    const int nt_e   = (tq == 3) ? 15 : 16;          // even tiles
    const int nt_o   = (tq == 3) ? 14 : 16;          // odd tiles

    switch (ns) {
    case 1:
        sweep<1>(sxb, tstart,     nt_e, afrag, nb, cnt, mx, zero4);
        sweep<1>(sxb, tstart + 1, nt_o, afrag, nb, cnt, mx, zero4);
        break;
    case 2:
        sweep<2>(sxb, tstart,     nt_e, afrag, nb, cnt, mx, zero4);
        sweep<2>(sxb, tstart + 1, nt_o, afrag, nb, cnt, mx, zero4);
        break;
    case 3:
        sweep<3>(sxb, tstart,     nt_e, afrag, nb, cnt, mx, zero4);
        sweep<3>(sxb, tstart + 1, nt_o, afrag, nb, cnt, mx, zero4);
        break;
    default:
        sweep<4>(sxb, tstart,     nt_e, afrag, nb, cnt, mx, zero4);
        sweep<4>(sxb, tstart + 1, nt_o, afrag, nb, cnt, mx, zero4);
        break;
    }

    // ---- col reduce over 16 lanes via DPP row_ror (no LDS pipe) ----
    #pragma unroll
    for (int kt = 0; kt < 2; ++kt) {
        #pragma unroll
        for (int r = 0; r < 4; ++r) {
            unsigned cv = cnt[kt][r];
            cv += (unsigned)__builtin_amdgcn_update_dpp(0, (int)cv, 0x128, 0xF, 0xF, true);
            cv += (unsigned)__builtin_amdgcn_update_dpp(0, (int)cv, 0x124, 0xF, 0xF, true);
            cv += (unsigned)__builtin_amdgcn_update_dpp(0, (int)cv, 0x122, 0xF, 0xF, true);
            cv += (unsigned)__builtin_amdgcn_update_dpp(0, (int)cv, 0x121, 0xF, 0xF, true);
            float mv = mx[kt][r];
            mv = fmaxf(mv, __builtin_bit_cast(float,
                 __builtin_amdgcn_update_dpp(0, __builtin_bit_cast(int, mv), 0x128, 0xF, 0xF, true)));
            mv = fmaxf(mv, __builtin_bit_cast(float,
                 __builtin_amdgcn_update_dpp(0, __builtin_bit_cast(int, mv), 0x124, 0xF, 0xF, true)));
            mv = fmaxf(mv, __builtin_bit_cast(float,
                 __builtin_amdgcn_update_dpp(0, __builtin_bit_cast(int, mv), 0x122, 0xF, 0xF, true)));
            mv = fmaxf(mv, __builtin_bit_cast(float,
                 __builtin_amdgcn_update_dpp(0, __builtin_bit_cast(int, mv), 0x121, 0xF, 0xF, true)));
            if (c == 0) {
                const int klo = (kp * 2 + kt) * 16 + g * 4 + r;   // 0..63
                pc[klo][tq] = cv;
                pm[klo][tq] = mv;
            }
        }
    }
    __syncthreads();

    if (tid < 64) {
        unsigned ct = pc[tid][0] + pc[tid][1] + pc[tid][2] + pc[tid][3];
        float mv = fmaxf(fmaxf(pm[tid][0], pm[tid][1]),
                         fmaxf(pm[tid][2], pm[tid][3]));
        const int pos = sub * 64 + tid;              // sorted position
        const int kk  = perm[pos];                   // original kernel id
        out[bc * (2 * NKER) + 2 * kk]     = (float)ct * (1.0f / T_LEN);
        out[bc * (2 * NKER) + 2 * kk + 1] = mv + bias_s[pos];
    }
}

extern "C" void kernel_launch(void* const* d_in, const int* in_sizes, int n_in,
                              void* d_out, int out_size, void* d_ws, size_t ws_size,
                              hipStream_t stream) {
    const float* x    = (const float*)d_in[0];
    const float* W    = (const float*)d_in[1];
    const float* bias = (const float*)d_in[2];
    float*       out  = (float*)d_out;

    const int Lmax = in_sizes[1] / NKER;

    unsigned* Wbf32  = (unsigned*)d_ws;                        // 64 KB
    int*      perm   = (int*)((char*)d_ws + 65536);            // 1 KB
    float*    bias_s = (float*)((char*)d_ws + 66560);          // 1 KB
    int*      ns_arr = (int*)((char*)d_ws + 67584);            // 1 KB
    int*      ns_s   = (int*)((char*)d_ws + 68608);            // 1 KB

    rocket_scan<<<dim3(NKER), dim3(64), 0, stream>>>(W, Lmax, ns_arr);
    rocket_rank<<<dim3(1), dim3(NKER), 0, stream>>>(ns_arr, bias,
                                                    perm, ns_s, bias_s);
    rocket_prep<<<dim3(NKER), dim3(64), 0, stream>>>(W, Lmax, perm, Wbf32);
    rocket_main<<<dim3(256, 4), dim3(THREADS), 0, stream>>>(
        x, bias_s, (const unsigned short*)Wbf32, perm, ns_s, out, Lmax);
}

// Round 18
// 44.423 us; speedup vs baseline: 1.6401x; 1.2087x over previous
//
#include <hip/hip_runtime.h>
#include <hip/hip_bf16.h>

#define T_LEN   2000
#define NKER    256
#define LPAD    128          // padded l-dim (Lmax <= 127)
#define NSTG    408          // staged entries per block (max read p' = 407)

typedef int   v4i __attribute__((ext_vector_type(4)));
typedef float v4f __attribute__((ext_vector_type(4)));

// raw-asm MFMA. "=&v" early-clobber: D must not alias A/B (multi-pass XDL).
__device__ inline v4f mfma_z(v4i a, v4i b, v4f c) {
    v4f d;
    asm volatile("v_mfma_f32_16x16x32_bf16 %0, %1, %2, %3"
                 : "=&v"(d) : "v"(a), "v"(b), "v"(c));
    return d;
}
__device__ inline void mfma_acc(v4f& acc, v4i a, v4i b) {
    asm volatile("v_mfma_f32_16x16x32_bf16 %0, %1, %2, %0"
                 : "+v"(acc) : "v"(a), "v"(b));
}
__device__ inline void mfma_acc_last(v4f& acc, v4i a, v4i b) {
    asm volatile("v_mfma_f32_16x16x32_bf16 %0, %1, %2, %0\n\ts_nop 7"
                 : "+v"(acc) : "v"(a), "v"(b));
}

__device__ inline unsigned f2bf(float f) {
    return (unsigned)__builtin_bit_cast(unsigned short, __float2bfloat16(f));
}

// ---------------------------------------------------------------------------
// Prep: dense bf16 weight bank [256][128], zero-padded (bias folded into
// main epilogue / finalize). 256 blocks x 64 thr, coalesced dword stores.
// ---------------------------------------------------------------------------
__global__ void rocket_prep(const float* __restrict__ W, int Lmax,
                            unsigned* __restrict__ Wbf32) {
    const int k = blockIdx.x;
    const int t = threadIdx.x;           // 0..63
    const int l0 = 2 * t, l1 = 2 * t + 1;
    float v0 = (l0 < Lmax) ? W[k * Lmax + l0] : 0.0f;
    float v1 = (l1 < Lmax) ? W[k * Lmax + l1] : 0.0f;
    Wbf32[k * (LPAD / 2) + t] = f2bf(v0) | (f2bf(v1) << 16);
}

// dense 4-step chain on the 8-slot window (R9's proven pattern, NS=4 only)
#define DO_KT4(kt, T)                                                        \
    {                                                                        \
        v4f acc = mfma_z(afrag[kt][0], w[(T + 0) & 7], zero4);               \
        mfma_acc(acc, afrag[kt][1], w[(T + 2) & 7]);                         \
        mfma_acc(acc, afrag[kt][2], w[(T + 4) & 7]);                         \
        mfma_acc_last(acc, afrag[kt][3], w[(T + 6) & 7]);                    \
        _Pragma("unroll")                                                    \
        for (int r = 0; r < 4; ++r) {                                        \
            cnt[kt][r] += (acc[r] > nb[kt][r]) ? 1u : 0u;                    \
            mx[kt][r]  = fmaxf(mx[kt][r], acc[r]);                           \
        }                                                                    \
    }

// ---------------------------------------------------------------------------
// Main: grid (256 bc, 2 khalf, 8 tchunk) x 256 threads (4 waves).
// Block covers kernels [kh*128, kh*128+128) x tiles [16tc, min(16tc+16,125)).
// Wave kp owns 2 ktiles (32 kernels) — waves cover DISJOINT kernels, so no
// cross-wave reduce / trailing barrier. LDS: 408 local shifted entries
// (7.4 KB): entry p' (16B) = bf16{x[256tc + p' - 63 ..]} at uint4-idx
// p' + p'/8. Inner loop = R9's dense 8-slot sliding window verbatim
// (1 ds_read_b128/tile). Partials (cnt,max) per (bc,tc,k) to global ws.
// ---------------------------------------------------------------------------
__global__ __launch_bounds__(256, 4) void rocket_main(
    const float* __restrict__ x, const float* __restrict__ bias,
    const unsigned short* __restrict__ Wbf, float2* __restrict__ part,
    int Lmax) {

    __shared__ __align__(16) uint4 sx8[464];      // idx max 457

    const int bc  = blockIdx.x;
    const int kh  = blockIdx.y;          // kernel half
    const int tc  = blockIdx.z;          // t-chunk of 16 tiles
    const int tid = threadIdx.x;
    const int c0  = (Lmax - 1) >> 1;

    // ---- stage 408 local entries: 2 consecutive entries per thread ----
    {
        const int base = tid * 2;
        if (base < NSTG) {
            const int q0 = tc * 256 + base;          // global entry index
            float xv[9];
            #pragma unroll
            for (int i = 0; i < 9; ++i) {
                int s = q0 + i - c0;
                xv[i] = (s >= 0 && s < T_LEN) ? x[bc * T_LEN + s] : 0.0f;
            }
            unsigned hb[9];
            #pragma unroll
            for (int i = 0; i < 9; ++i) hb[i] = f2bf(xv[i]);
            #pragma unroll
            for (int i = 0; i < 2; ++i) {
                int p = base + i;
                uint4 v;
                v.x = hb[i]     | (hb[i + 1] << 16);
                v.y = hb[i + 2] | (hb[i + 3] << 16);
                v.z = hb[i + 4] | (hb[i + 5] << 16);
                v.w = hb[i + 6] | (hb[i + 7] << 16);
                sx8[p + (p >> 3)] = v;
            }
        }
    }
    __syncthreads();

    const int lane = tid & 63;
    const int kp   = tid >> 6;           // 0..3
    const int g    = lane >> 4;
    const int c    = lane & 15;

    const int gt0 = kh * 8 + kp * 2;     // global ktiles
    const int gt1 = gt0 + 1;

    // ---- A fragments: 2 ktiles x 4 k-steps (32 VGPR) ----
    v4i afrag[2][4];
    #pragma unroll
    for (int kt = 0; kt < 2; ++kt) {
        const int tld = (kt == 0) ? gt0 : gt1;
        #pragma unroll
        for (int s = 0; s < 4; ++s) {
            const unsigned short* src =
                Wbf + (tld * 16 + c) * LPAD + s * 32 + g * 8;
            afrag[kt][s] = *reinterpret_cast<const v4i*>(src);
        }
    }

    // ---- negated bias per owned row ----
    float nb[2][4];
    #pragma unroll
    for (int kt = 0; kt < 2; ++kt) {
        const int tld = (kt == 0) ? gt0 : gt1;
        float4 bv = *reinterpret_cast<const float4*>(bias + tld * 16 + g * 4);
        nb[kt][0] = -bv.x; nb[kt][1] = -bv.y;
        nb[kt][2] = -bv.z; nb[kt][3] = -bv.w;
    }

    unsigned cnt[2][4] = {};
    float    mx[2][4];
    #pragma unroll
    for (int kt = 0; kt < 2; ++kt)
        #pragma unroll
        for (int r = 0; r < 4; ++r) mx[kt][r] = -__builtin_inff();

    v4f zero4 = {0.f, 0.f, 0.f, 0.f};
    asm("" : "+v"(zero4));   // pin: persistent zero C-quad

    const int pb = g * 8 + c;                        // 0..39
    const unsigned voff = (unsigned)(pb + (pb >> 3)) << 4;
    const char* p = (const char*)sx8 + voff;         // local group 0

    const bool full = (tc < 7);                      // 16 vs 13 tiles
    const int  nms  = full ? 2 : 1;

    // ---- window prologue: local groups 0..7 ----
    v4i w[8];
    #pragma unroll
    for (int j = 0; j < 8; ++j)
        w[j] = *reinterpret_cast<const v4i*>(p + 288 * j);

    #pragma unroll 1
    for (int ms = 0; ms < nms; ++ms) {
        DO_KT4(0, 0) DO_KT4(1, 0)
        DO_KT4(0, 1) DO_KT4(1, 1)
        w[0] = *reinterpret_cast<const v4i*>(p + 288 * 8);
        w[1] = *reinterpret_cast<const v4i*>(p + 288 * 9);
        DO_KT4(0, 2) DO_KT4(1, 2)
        DO_KT4(0, 3) DO_KT4(1, 3)
        w[2] = *reinterpret_cast<const v4i*>(p + 288 * 10);
        w[3] = *reinterpret_cast<const v4i*>(p + 288 * 11);
        DO_KT4(0, 4) DO_KT4(1, 4)
        DO_KT4(0, 5) DO_KT4(1, 5)
        w[4] = *reinterpret_cast<const v4i*>(p + 288 * 12);
        w[5] = *reinterpret_cast<const v4i*>(p + 288 * 13);
        DO_KT4(0, 6) DO_KT4(1, 6)
        DO_KT4(0, 7) DO_KT4(1, 7)
        w[6] = *reinterpret_cast<const v4i*>(p + 288 * 14);
        w[7] = *reinterpret_cast<const v4i*>(p + 288 * 15);
        p += 2304;                                   // 8 groups
    }

    if (!full) {
        // tail tiles local 8..12 (global 120..124): plain 4-read path
        #pragma unroll 1
        for (int tt = 0; tt < 5; ++tt) {
            v4i b0 = *reinterpret_cast<const v4i*>(p + 288 * (tt + 0));
            v4i b1 = *reinterpret_cast<const v4i*>(p + 288 * (tt + 2));
            v4i b2 = *reinterpret_cast<const v4i*>(p + 288 * (tt + 4));
            v4i b3 = *reinterpret_cast<const v4i*>(p + 288 * (tt + 6));
            #pragma unroll
            for (int kt = 0; kt < 2; ++kt) {
                v4f acc = mfma_z(afrag[kt][0], b0, zero4);
                mfma_acc(acc, afrag[kt][1], b1);
                mfma_acc(acc, afrag[kt][2], b2);
                mfma_acc_last(acc, afrag[kt][3], b3);
                #pragma unroll
                for (int r = 0; r < 4; ++r) {
                    cnt[kt][r] += (acc[r] > nb[kt][r]) ? 1u : 0u;
                    mx[kt][r]  = fmaxf(mx[kt][r], acc[r]);
                }
            }
        }
    }

    // ---- col reduce over 16 lanes via DPP row_ror, write partials ----
    #pragma unroll
    for (int kt = 0; kt < 2; ++kt) {
        #pragma unroll
        for (int r = 0; r < 4; ++r) {
            unsigned cv = cnt[kt][r];
            cv += (unsigned)__builtin_amdgcn_update_dpp(0, (int)cv, 0x128, 0xF, 0xF, true);
            cv += (unsigned)__builtin_amdgcn_update_dpp(0, (int)cv, 0x124, 0xF, 0xF, true);
            cv += (unsigned)__builtin_amdgcn_update_dpp(0, (int)cv, 0x122, 0xF, 0xF, true);
            cv += (unsigned)__builtin_amdgcn_update_dpp(0, (int)cv, 0x121, 0xF, 0xF, true);
            float mv = mx[kt][r];
            mv = fmaxf(mv, __builtin_bit_cast(float,
                 __builtin_amdgcn_update_dpp(0, __builtin_bit_cast(int, mv), 0x128, 0xF, 0xF, true)));
            mv = fmaxf(mv, __builtin_bit_cast(float,
                 __builtin_amdgcn_update_dpp(0, __builtin_bit_cast(int, mv), 0x124, 0xF, 0xF, true)));
            mv = fmaxf(mv, __builtin_bit_cast(float,
                 __builtin_amdgcn_update_dpp(0, __builtin_bit_cast(int, mv), 0x122, 0xF, 0xF, true)));
            mv = fmaxf(mv, __builtin_bit_cast(float,
                 __builtin_amdgcn_update_dpp(0, __builtin_bit_cast(int, mv), 0x121, 0xF, 0xF, true)));
            if (c == 0) {
                const int krow = ((kh * 8 + kp * 2 + kt) * 16) + g * 4 + r;
                part[(bc * 8 + tc) * NKER + krow] =
                    make_float2((float)cv, mv);
            }
        }
    }
}

// ---------------------------------------------------------------------------
// Finalize: reduce 8 t-chunk partials per (bc, k); bias added to max here.
// ---------------------------------------------------------------------------
__global__ void rocket_fin(const float2* __restrict__ part,
                           const float* __restrict__ bias,
                           float* __restrict__ out) {
    const int bc = blockIdx.x;
    const int k  = threadIdx.x;
    float cnt = 0.0f, mx = -__builtin_inff();
    #pragma unroll
    for (int tc = 0; tc < 8; ++tc) {
        float2 v = part[(bc * 8 + tc) * NKER + k];
        cnt += v.x;
        mx = fmaxf(mx, v.y);
    }
    out[bc * (2 * NKER) + 2 * k]     = cnt * (1.0f / T_LEN);
    out[bc * (2 * NKER) + 2 * k + 1] = mx + bias[k];
}

extern "C" void kernel_launch(void* const* d_in, const int* in_sizes, int n_in,
                              void* d_out, int out_size, void* d_ws, size_t ws_size,
                              hipStream_t stream) {
    const float* x    = (const float*)d_in[0];
    const float* W    = (const float*)d_in[1];
    const float* bias = (const float*)d_in[2];
    float*       out  = (float*)d_out;

    const int Lmax = in_sizes[1] / NKER;

    unsigned* Wbf32 = (unsigned*)d_ws;                       // 64 KB
    float2*   part  = (float2*)((char*)d_ws + 65536);        // 4 MB

    rocket_prep<<<dim3(NKER), dim3(64), 0, stream>>>(W, Lmax, Wbf32);
    rocket_main<<<dim3(256, 2, 8), dim3(256), 0, stream>>>(
        x, bias, (const unsigned short*)Wbf32, part, Lmax);
    rocket_fin<<<dim3(256), dim3(NKER), 0, stream>>>(part, bias, out);
}

// Round 22
// 37.819 us; speedup vs baseline: 1.9265x; 1.1746x over previous
//
#include <hip/hip_runtime.h>
#include <hip/hip_bf16.h>

#define T_LEN   2000
#define NKER    256
#define LPAD    128          // padded l-dim (Lmax <= 127)
#define NE      2128         // shifted entries staged (>= T_LEN + Lmax - 1)
#define THREADS 512

typedef int   v4i __attribute__((ext_vector_type(4)));
typedef float v4f __attribute__((ext_vector_type(4)));

// raw-asm MFMA. "=&v" early-clobber: D must not alias A/B (multi-pass XDL);
// R7's absmax=4.3 failure was the allocator aliasing D with a dying B input.
__device__ inline v4f mfma_z(v4i a, v4i b, v4f c) {
    v4f d;
    asm volatile("v_mfma_f32_16x16x32_bf16 %0, %1, %2, %3"
                 : "=&v"(d) : "v"(a), "v"(b), "v"(c));
    return d;
}
__device__ inline void mfma_acc(v4f& acc, v4i a, v4i b) {
    asm volatile("v_mfma_f32_16x16x32_bf16 %0, %1, %2, %0"
                 : "+v"(acc) : "v"(a), "v"(b));
}
// chain-final MFMA: s_nop covers MFMA->VALU RAW hazard (opaque to compiler)
__device__ inline void mfma_acc_last(v4f& acc, v4i a, v4i b) {
    asm volatile("v_mfma_f32_16x16x32_bf16 %0, %1, %2, %0\n\ts_nop 7"
                 : "+v"(acc) : "v"(a), "v"(b));
}

__device__ inline unsigned f2bf(float f) {
    return (unsigned)__builtin_bit_cast(unsigned short, __float2bfloat16(f));
}

// ---------------------------------------------------------------------------
// Prep: dense bf16 weight bank [256][128], zero-padded (no bias tap -- bias
// is applied in the main epilogue: cnt uses acc > -b, max adds b at the end).
// ---------------------------------------------------------------------------
__global__ void rocket_prep(const float* __restrict__ W, int Lmax,
                            unsigned* __restrict__ Wbf32) {
    const int k = blockIdx.x;
    const int t = threadIdx.x;           // 0..63
    const int l0 = 2 * t, l1 = 2 * t + 1;
    float v0 = (l0 < Lmax) ? W[k * Lmax + l0] : 0.0f;
    float v1 = (l1 < Lmax) ? W[k * Lmax + l1] : 0.0f;
    Wbf32[k * (LPAD / 2) + t] = f2bf(v0) | (f2bf(v1) << 16);
}

// ---------------------------------------------------------------------------
// Main: grid (256 bc, 4 sub) x 512 threads (8 waves = 2 kp x 4 tq).
// Wave: 2 ktiles (32 kernels) x 32/29 t-tiles (split 32/32/32/29).
// B-entry for (tile tau, slot s) is J = tau + 2s at LDS byte 288*J + voff --
// an arithmetic progression. 8-deep per-lane register window w[J%8] turns
// 4 ds_read_b128/tile into 1/tile (steady state), with all addresses folded
// to base + compile-time immediates. Epilogue: cnt += (acc > -bias), running
// max; DPP row_ror 16-lane column reduce; bias added to max at final write.
// ---------------------------------------------------------------------------
__global__ __launch_bounds__(THREADS, 4) void rocket_main(
    const float* __restrict__ x, const float* __restrict__ bias,
    const unsigned short* __restrict__ Wbf, float* __restrict__ out,
    int Lmax) {

    __shared__ __align__(16) uint4 sx8[2400];     // idx max 2392
    __shared__ unsigned pc[64][4];
    __shared__ float    pm[64][4];

    const int bc  = blockIdx.x;
    const int sub = blockIdx.y;          // kernel group of 64
    const int tid = threadIdx.x;
    const int c0  = (Lmax - 1) >> 1;

    // ---- stage shifted entries: 5 consecutive entries per thread ----
    {
        const int base = tid * 5;
        if (base < NE) {
            float xv[12];
            #pragma unroll
            for (int i = 0; i < 12; ++i) {
                int s = base + i - c0;
                xv[i] = (s >= 0 && s < T_LEN) ? x[bc * T_LEN + s] : 0.0f;
            }
            unsigned hb[12];
            #pragma unroll
            for (int i = 0; i < 12; ++i) hb[i] = f2bf(xv[i]);
            #pragma unroll
            for (int i = 0; i < 5; ++i) {
                int p = base + i;
                if (p < NE) {
                    uint4 v;
                    v.x = hb[i]     | (hb[i + 1] << 16);
                    v.y = hb[i + 2] | (hb[i + 3] << 16);
                    v.z = hb[i + 4] | (hb[i + 5] << 16);
                    v.w = hb[i + 6] | (hb[i + 7] << 16);
                    sx8[p + (p >> 3)] = v;
                }
            }
        }
    }

    const int lane = tid & 63;
    const int wid  = tid >> 6;
    const int kp   = wid >> 2;       // 0..1: local ktile-pair
    const int tq   = wid & 3;        // t quarter
    const int g    = lane >> 4;
    const int c    = lane & 15;

    // ---- A fragments: 2 ktiles x 4 k-steps in registers (32 VGPR) ----
    v4i afrag[2][4];
    #pragma unroll
    for (int kt = 0; kt < 2; ++kt) {
        #pragma unroll
        for (int s = 0; s < 4; ++s) {
            const unsigned short* src =
                Wbf + ((sub * 4 + kp * 2 + kt) * 16 + c) * LPAD + s * 32 + g * 8;
            afrag[kt][s] = *reinterpret_cast<const v4i*>(src);
        }
    }

    // ---- negated bias per owned row: nb[kt][r] for rows g*4+r ----
    float nb[2][4];
    #pragma unroll
    for (int kt = 0; kt < 2; ++kt) {
        float4 bv = *reinterpret_cast<const float4*>(
            bias + sub * 64 + (kp * 2 + kt) * 16 + g * 4);
        nb[kt][0] = -bv.x; nb[kt][1] = -bv.y;
        nb[kt][2] = -bv.z; nb[kt][3] = -bv.w;
    }

    __syncthreads();

    unsigned cnt[2][4] = {};
    float    mx[2][4];
    #pragma unroll
    for (int kt = 0; kt < 2; ++kt)
        #pragma unroll
        for (int r = 0; r < 4; ++r) mx[kt][r] = -__builtin_inff();

    v4f zero4 = {0.f, 0.f, 0.f, 0.f};
    asm("" : "+v"(zero4));   // pin: persistent zero C-quad

    const int pb = g * 8 + c;                        // 0..39
    const unsigned voff = (unsigned)(pb + (pb >> 3)) << 4;

    // per-tile compute: 2 chains of 4 MFMA + cnt/max epilogue
    auto do_tile = [&](v4i b0, v4i b1, v4i b2, v4i b3) {
        #pragma unroll
        for (int kt = 0; kt < 2; ++kt) {
            v4f acc = mfma_z(afrag[kt][0], b0, zero4);
            mfma_acc(acc, afrag[kt][1], b1);
            mfma_acc(acc, afrag[kt][2], b2);
            mfma_acc_last(acc, afrag[kt][3], b3);
            #pragma unroll
            for (int r = 0; r < 4; ++r) {
                cnt[kt][r] += (acc[r] > nb[kt][r]) ? 1u : 0u;
                mx[kt][r]  = fmaxf(mx[kt][r], acc[r]);
            }
        }
    };

    const int tstart = tq * 32;                      // 32/32/32/29 split
    const int nms    = (tq == 3) ? 3 : 4;            // 8-tile macro-steps

    // entry J lives at byte 288*J + voff (idx = 18J + pb + (pb>>3))
    const char* p = (const char*)sx8 + voff + 288u * (unsigned)tstart;

    // ---- window prologue: J = tstart..tstart+7 in slots 0..7 ----
    v4i w[8];
    #pragma unroll
    for (int j = 0; j < 8; ++j)
        w[j] = *reinterpret_cast<const v4i*>(p + 288 * j);

    #pragma unroll 1
    for (int ms = 0; ms < nms; ++ms) {
        #pragma unroll
        for (int m = 0; m < 4; ++m) {
            // tile 2m: slots (2m+2s)&7
            do_tile(w[(2*m + 0) & 7], w[(2*m + 2) & 7],
                    w[(2*m + 4) & 7], w[(2*m + 6) & 7]);
            // tile 2m+1: slots (2m+1+2s)&7
            do_tile(w[(2*m + 1) & 7], w[(2*m + 3) & 7],
                    w[(2*m + 5) & 7], w[(2*m + 7) & 7]);
            // slide: J+8, J+9 into freed slots
            w[(2*m + 0) & 7] = *reinterpret_cast<const v4i*>(p + 288 * (2*m + 8));
            w[(2*m + 1) & 7] = *reinterpret_cast<const v4i*>(p + 288 * (2*m + 9));
        }
        p += 2304;                                   // 8 tiles * 288
    }

    if (tq == 3) {
        // tail tiles 120..124 (rel 0..4 from p): plain 4-read path
        #pragma unroll
        for (int tt = 0; tt < 5; ++tt) {
            v4i b0 = *reinterpret_cast<const v4i*>(p + 288 * (tt + 0));
            v4i b1 = *reinterpret_cast<const v4i*>(p + 288 * (tt + 2));
            v4i b2 = *reinterpret_cast<const v4i*>(p + 288 * (tt + 4));
            v4i b3 = *reinterpret_cast<const v4i*>(p + 288 * (tt + 6));
            do_tile(b0, b1, b2, b3);
        }
    }

    // ---- col reduce over 16 lanes via DPP row_ror (no LDS pipe) ----
    #pragma unroll
    for (int kt = 0; kt < 2; ++kt) {
        #pragma unroll
        for (int r = 0; r < 4; ++r) {
            unsigned cv = cnt[kt][r];
            cv += (unsigned)__builtin_amdgcn_update_dpp(0, (int)cv, 0x128, 0xF, 0xF, true);
            cv += (unsigned)__builtin_amdgcn_update_dpp(0, (int)cv, 0x124, 0xF, 0xF, true);
            cv += (unsigned)__builtin_amdgcn_update_dpp(0, (int)cv, 0x122, 0xF, 0xF, true);
            cv += (unsigned)__builtin_amdgcn_update_dpp(0, (int)cv, 0x121, 0xF, 0xF, true);
            float mv = mx[kt][r];
            mv = fmaxf(mv, __builtin_bit_cast(float,
                 __builtin_amdgcn_update_dpp(0, __builtin_bit_cast(int, mv), 0x128, 0xF, 0xF, true)));
            mv = fmaxf(mv, __builtin_bit_cast(float,
                 __builtin_amdgcn_update_dpp(0, __builtin_bit_cast(int, mv), 0x124, 0xF, 0xF, true)));
            mv = fmaxf(mv, __builtin_bit_cast(float,
                 __builtin_amdgcn_update_dpp(0, __builtin_bit_cast(int, mv), 0x122, 0xF, 0xF, true)));
            mv = fmaxf(mv, __builtin_bit_cast(float,
                 __builtin_amdgcn_update_dpp(0, __builtin_bit_cast(int, mv), 0x121, 0xF, 0xF, true)));
            if (c == 0) {
                const int klo = (kp * 2 + kt) * 16 + g * 4 + r;   // 0..63
                pc[klo][tq] = cv;
                pm[klo][tq] = mv;
            }
        }
    }
    __syncthreads();

    if (tid < 64) {
        unsigned ct = pc[tid][0] + pc[tid][1] + pc[tid][2] + pc[tid][3];
        float mv = fmaxf(fmaxf(pm[tid][0], pm[tid][1]),
                         fmaxf(pm[tid][2], pm[tid][3]));
        const int kk = sub * 64 + tid;
        out[bc * (2 * NKER) + 2 * kk]     = (float)ct * (1.0f / T_LEN);
        out[bc * (2 * NKER) + 2 * kk + 1] = mv + bias[kk];   // bias folded here
    }
}

extern "C" void kernel_launch(void* const* d_in, const int* in_sizes, int n_in,
                              void* d_out, int out_size, void* d_ws, size_t ws_size,
                              hipStream_t stream) {
    const float* x    = (const float*)d_in[0];
    const float* W    = (const float*)d_in[1];
    const float* bias = (const float*)d_in[2];
    float*       out  = (float*)d_out;

    const int Lmax = in_sizes[1] / NKER;

    unsigned* Wbf32 = (unsigned*)d_ws;             // 256*128*2 = 64 KB

    rocket_prep<<<dim3(NKER), dim3(64), 0, stream>>>(W, Lmax, Wbf32);
    rocket_main<<<dim3(256, 4), dim3(THREADS), 0, stream>>>(
        x, bias, (const unsigned short*)Wbf32, out, Lmax);
}